// Round 1
// 462.640 us; speedup vs baseline: 1.2865x; 1.2865x over previous
//
#include <hip/hip_runtime.h>
#include <cstdint>
#include <cstddef>

typedef __bf16 bf16;
typedef __bf16 bf16x4 __attribute__((ext_vector_type(4)));
typedef __bf16 bf16x8 __attribute__((ext_vector_type(8)));
typedef float f32x4 __attribute__((ext_vector_type(4)));
typedef float f32x16 __attribute__((ext_vector_type(16)));
typedef unsigned int uint2v __attribute__((ext_vector_type(2)));

#define SLD 40  // GEMM LDS row stride (elements): 80B -> 2-way (free) bank pattern

// ---------------------------------------------------------------------------
// permlane32_swap: exchange DST.row1 <-> SRC.row0.
// With a==b==x: first = {x.lo | x.lo->hi}, second = {x.hi->lo | x.hi},
// so f(first, second) == f(own, partner) at every lane.
// ---------------------------------------------------------------------------
__device__ __forceinline__ void plswap(unsigned& a, unsigned& b) {
  uint2v r = __builtin_amdgcn_permlane32_swap(a, b, false, false);
  a = r[0];
  b = r[1];
}
__device__ __forceinline__ float xhalf_max(float x) {
  unsigned a = __float_as_uint(x), b = a;
  plswap(a, b);
  return fmaxf(__uint_as_float(a), __uint_as_float(b));
}
__device__ __forceinline__ float xhalf_sum(float x) {
  unsigned a = __float_as_uint(x), b = a;
  plswap(a, b);
  return __uint_as_float(a) + __uint_as_float(b);
}
__device__ __forceinline__ unsigned cvtpk(float lo, float hi) {
  unsigned r;
  asm("v_cvt_pk_bf16_f32 %0, %1, %2" : "=v"(r) : "v"(lo), "v"(hi));
  return r;
}

// Build one PV B-fragment (P^T[k][q], k-chunk of 16) from 8 f32 P values.
// X reg i holds k = 8*(i>>2) + (i&3) + 4*hi for this lane (32x32 C layout).
// Pair (g0, g0+1): pack+swap so lo lanes end with k = base+0..7, hi k = base+8..15.
template <int G0>
__device__ __forceinline__ bf16x8 build_pfrag(const f32x16& X) {
  unsigned a0 = cvtpk(X[G0 * 4 + 0], X[G0 * 4 + 1]);
  unsigned b0 = cvtpk(X[G0 * 4 + 4], X[G0 * 4 + 5]);
  plswap(a0, b0);
  unsigned a1 = cvtpk(X[G0 * 4 + 2], X[G0 * 4 + 3]);
  unsigned b1 = cvtpk(X[G0 * 4 + 6], X[G0 * 4 + 7]);
  plswap(a1, b1);
  union {
    unsigned w[4];
    bf16x8 v;
  } u;
  u.w[0] = a0;  // elements 0,1
  u.w[1] = a1;  // elements 2,3
  u.w[2] = b0;  // elements 4,5
  u.w[3] = b1;  // elements 6,7
  return u.v;
}

// ---------------------------------------------------------------------------
// NT GEMM: C[M,N] = A[M,K] @ B[N,K]^T + bias[N], f32 accum.
// f32 operands (A_F32/B_F32): load+cvt staging. bf16: vector-load staging.
// 128x128 tile, BK=32, 4 waves (2x2), each wave 64x64 = 4x4 mfma 16x16x32.
// MODE 0: C row-major [M,N], bias added          (CT=float for d_out)
// MODE 1: scatter to Q/K attn layout [b][h][t][d]  (t=s*8+o/1024)
// MODE 2: scatter to V^T layout      [b][h][d][t]
// MODE 3: split-K partial: blockIdx.y owns K-slice of 1024, writes f32
//         partial (no bias) at C + blockIdx.y*M*N.
// oscale: epilogue scale (acc+bias)*oscale  (used to fold log2e/sqrt(HID)
//         into the Q projection so attention works in the exp2 domain).
// ---------------------------------------------------------------------------
template <int MODE, bool A_F32, bool B_F32, typename CT>
__global__ __launch_bounds__(256)
void gemm_nt(const void* __restrict__ Ap, const void* __restrict__ Bp,
             const float* __restrict__ bias, CT* __restrict__ C,
             int M, int N, int K, float oscale) {
  __shared__ bf16 As[128 * SLD];
  __shared__ bf16 Bs[128 * SLD];
  const int tid = threadIdx.x;
  const int w = tid >> 6, l = tid & 63;
  const int l15 = l & 15, quad = l >> 4;
  const int tiles_n = N >> 7;
  const int tm = (blockIdx.x / tiles_n) << 7;
  const int tn = (blockIdx.x % tiles_n) << 7;
  const int wm = (w >> 1) << 6;
  const int wn = (w & 1) << 6;

  f32x4 acc[4][4] = {};

  // f32 staging geometry: each thread covers 16 elements of one row
  const int frow = tid >> 1;
  const int fch = (tid & 1) * 16;

  const int kbeg = (MODE == 3) ? blockIdx.y * 1024 : 0;
  const int kend = (MODE == 3) ? kbeg + 1024 : K;

  for (int k0 = kbeg; k0 < kend; k0 += 32) {
    __syncthreads();
    if (A_F32) {
      const float* src = (const float*)Ap + (size_t)(tm + frow) * K + k0 + fch;
      f32x4 x0 = *(const f32x4*)(src);
      f32x4 x1 = *(const f32x4*)(src + 4);
      f32x4 x2 = *(const f32x4*)(src + 8);
      f32x4 x3 = *(const f32x4*)(src + 12);
      bf16x8 y0, y1;
#pragma unroll
      for (int j = 0; j < 4; ++j) {
        y0[j] = (bf16)x0[j]; y0[j + 4] = (bf16)x1[j];
        y1[j] = (bf16)x2[j]; y1[j + 4] = (bf16)x3[j];
      }
      *(bf16x8*)(As + frow * SLD + fch) = y0;
      *(bf16x8*)(As + frow * SLD + fch + 8) = y1;
    } else {
      const bf16* Ab = (const bf16*)Ap;
#pragma unroll
      for (int pc = 0; pc < 2; ++pc) {
        const int c = tid + pc * 256;          // 512 chunks of 16B
        const int r = c >> 2, col = (c & 3) * 8;
        *(bf16x8*)(As + r * SLD + col) =
            *(const bf16x8*)(Ab + (size_t)(tm + r) * K + k0 + col);
      }
    }
    if (B_F32) {
      const float* src = (const float*)Bp + (size_t)(tn + frow) * K + k0 + fch;
      f32x4 x0 = *(const f32x4*)(src);
      f32x4 x1 = *(const f32x4*)(src + 4);
      f32x4 x2 = *(const f32x4*)(src + 8);
      f32x4 x3 = *(const f32x4*)(src + 12);
      bf16x8 y0, y1;
#pragma unroll
      for (int j = 0; j < 4; ++j) {
        y0[j] = (bf16)x0[j]; y0[j + 4] = (bf16)x1[j];
        y1[j] = (bf16)x2[j]; y1[j + 4] = (bf16)x3[j];
      }
      *(bf16x8*)(Bs + frow * SLD + fch) = y0;
      *(bf16x8*)(Bs + frow * SLD + fch + 8) = y1;
    } else {
      const bf16* Bb = (const bf16*)Bp;
#pragma unroll
      for (int pc = 0; pc < 2; ++pc) {
        const int c = tid + pc * 256;
        const int r = c >> 2, col = (c & 3) * 8;
        *(bf16x8*)(Bs + r * SLD + col) =
            *(const bf16x8*)(Bb + (size_t)(tn + r) * K + k0 + col);
      }
    }
    __syncthreads();

    bf16x8 af[4], bfr[4];
#pragma unroll
    for (int i = 0; i < 4; ++i)
      af[i] = *(const bf16x8*)(As + (wm + i * 16 + l15) * SLD + quad * 8);
#pragma unroll
    for (int j = 0; j < 4; ++j)
      bfr[j] = *(const bf16x8*)(Bs + (wn + j * 16 + l15) * SLD + quad * 8);
#pragma unroll
    for (int i = 0; i < 4; ++i)
#pragma unroll
      for (int j = 0; j < 4; ++j)
        acc[i][j] = __builtin_amdgcn_mfma_f32_16x16x32_bf16(af[i], bfr[j], acc[i][j], 0, 0, 0);
  }

  const size_t koff = (MODE == 3) ? (size_t)blockIdx.y * M * N : 0;
#pragma unroll
  for (int i = 0; i < 4; ++i) {
#pragma unroll
    for (int j = 0; j < 4; ++j) {
      const int n = tn + wn + j * 16 + l15;
      const float bv = (MODE == 3) ? 0.f : bias[n];
#pragma unroll
      for (int r = 0; r < 4; ++r) {
        const int m = tm + wm + i * 16 + quad * 4 + r;
        const float v = (MODE == 3) ? acc[i][j][r] : (acc[i][j][r] + bv) * oscale;
        size_t idx;
        if (MODE == 0 || MODE == 3) {
          idx = koff + (size_t)m * N + n;
        } else {
          const int b = m >> 8, s = m & 255;
          const int t = (s << 3) | (n >> 10);
          const int h = (n >> 7) & 7;
          const int d = n & 127;
          if (MODE == 1)
            idx = ((size_t)(b * 8 + h) * 2048 + t) * 128 + d;
          else
            idx = ((size_t)(b * 8 + h) * 128 + d) * 2048 + t;
        }
        C[idx] = (CT)v;
      }
    }
  }
}

// Sum 8 split-K partials + bias -> f32 out. 1024x1024 elements, f32x4.
__global__ __launch_bounds__(256)
void splitk_reduce(const float* __restrict__ P, const float* __restrict__ bias,
                   float* __restrict__ out) {
  const int i = (blockIdx.x * 256 + threadIdx.x) * 4;  // element index
  const int n = i & 1023;
  f32x4 s = *(const f32x4*)(bias + n);
#pragma unroll
  for (int kc = 0; kc < 8; ++kc)
    s += *(const f32x4*)(P + (size_t)kc * 1048576 + i);
  *(f32x4*)(out + i) = s;
}

// ---------------------------------------------------------------------------
// Flash attention, 32x32 swapped-operand structure (learn_hip m214 ladder).
// Q,K: [bh][2048][128] bf16 (Q pre-scaled by log2e/32), V^T: [bh][128][2048].
// Block = 4 waves x 32 q-rows = 128 q-rows; KVBLK = 64 keys/iter, 32 iters.
// QK^T computed swapped (A=K, B=Q) -> S^T: col=q=lane&31 (q lane-local:
// softmax m/l are per-lane scalars; cross-half via permlane32_swap).
// PV computed as O^T = V^T x P^T (A=V^T, B=P^T) so O keeps q lane-local.
// P^T frags built in-register via v_cvt_pk_bf16_f32 + permlane32_swap.
// K LDS rows 256B, XOR swizzle (row&15)<<4 -> 2-way (free) ds_read_b128.
// V LDS rows 128B, XOR swizzle (row&7)<<4  -> 4-way residual.
// Async stage: global->reg issued before compute, reg->LDS after barrier.
// ---------------------------------------------------------------------------
__global__ __launch_bounds__(256, 2)
void attn_kernel(const bf16* __restrict__ Q, const bf16* __restrict__ Kc,
                 const bf16* __restrict__ Vt, bf16* __restrict__ O2) {
  __shared__ bf16x8 KsV[1024];  // 64 keys x 128 d  (16KB)
  __shared__ bf16x8 VsV[1024];  // 128 d  x 64 keys (16KB)
  char* KsB = (char*)KsV;
  char* VsB = (char*)VsV;

  const int tid = threadIdx.x;
  const int w = tid >> 6, l = tid & 63;
  const int l31 = l & 31, hi = l >> 5;
  // XCD-chunked swizzle: 512 blocks, 8 XCDs -> 64 consecutive wg per XCD
  // (= 4 full (b,h) groups, so K/V tiles are reused within one XCD L2).
  const int wg = ((blockIdx.x & 7) << 6) | (blockIdx.x >> 3);
  const int bh = wg >> 4;
  const int qc = wg & 15;
  const int b = bh >> 3, h = bh & 7;
  const int q0w = qc * 128 + w * 32;
  const size_t qkbase = (size_t)bh * 2048 * 128;
  const size_t vbase = (size_t)bh * 128 * 2048;

  // Q fragments (B-operand of mfma(K,Q)): lane holds Q[q=l31][d=dc*16+hi*8+j]
  bf16x8 qf[8];
#pragma unroll
  for (int dc = 0; dc < 8; ++dc)
    qf[dc] = *(const bf16x8*)(Q + qkbase + (size_t)(q0w + l31) * 128 + dc * 16 + hi * 8);

  f32x16 oacc[4] = {};  // O^T: [dt] rows d=dt*32+{8g+4hi+r}, col q=l31
  float m = -1e30f, lsum = 0.f;

  bf16x8 kreg[4], vreg[4];
  auto stage_load = [&](int kk) {
#pragma unroll
    for (int pc = 0; pc < 4; ++pc) {
      const int c = tid + pc * 256;
      kreg[pc] = *(const bf16x8*)(Kc + qkbase + (size_t)(kk + (c >> 4)) * 128 + (c & 15) * 8);
      vreg[pc] = *(const bf16x8*)(Vt + vbase + (size_t)(c >> 3) * 2048 + kk + (c & 7) * 8);
    }
  };
  auto stage_write = [&]() {
#pragma unroll
    for (int pc = 0; pc < 4; ++pc) {
      const int c = tid + pc * 256;
      const int kr = c >> 4, kcol = c & 15;
      *(bf16x8*)(KsB + ((kr * 256 + kcol * 16) ^ ((kr & 15) << 4))) = kreg[pc];
      const int vr = c >> 3, vcol = c & 7;
      *(bf16x8*)(VsB + ((vr * 128 + vcol * 16) ^ ((vr & 7) << 4))) = vreg[pc];
    }
  };

  stage_load(0);
  stage_write();
  __syncthreads();

  for (int it = 0; it < 32; ++it) {
    if (it < 31) stage_load((it + 1) * 64);  // issue early: hides under compute

    // ---- QK^T (swapped): S^T[key][q], key subtiles 0..31 (sa), 32..63 (sb)
    f32x16 sa = {}, sb = {};
#pragma unroll
    for (int dc = 0; dc < 8; ++dc) {
      const int colb = dc * 32 + hi * 16;
      bf16x8 ka = *(const bf16x8*)(KsB + ((l31 * 256 + colb) ^ ((l31 & 15) << 4)));
      bf16x8 kb = *(const bf16x8*)(KsB + (((32 + l31) * 256 + colb) ^ ((l31 & 15) << 4)));
      sa = __builtin_amdgcn_mfma_f32_32x32x16_bf16(ka, qf[dc], sa, 0, 0, 0);
      sb = __builtin_amdgcn_mfma_f32_32x32x16_bf16(kb, qf[dc], sb, 0, 0, 0);
    }

    // ---- online softmax (exp2 domain; Q pre-scaled by log2e/32)
    float mt;
    {
      float a0 = fmaxf(fmaxf(sa[0], sa[1]), fmaxf(sa[2], sa[3]));
      float a1 = fmaxf(fmaxf(sa[4], sa[5]), fmaxf(sa[6], sa[7]));
      float a2 = fmaxf(fmaxf(sa[8], sa[9]), fmaxf(sa[10], sa[11]));
      float a3 = fmaxf(fmaxf(sa[12], sa[13]), fmaxf(sa[14], sa[15]));
      float b0 = fmaxf(fmaxf(sb[0], sb[1]), fmaxf(sb[2], sb[3]));
      float b1 = fmaxf(fmaxf(sb[4], sb[5]), fmaxf(sb[6], sb[7]));
      float b2 = fmaxf(fmaxf(sb[8], sb[9]), fmaxf(sb[10], sb[11]));
      float b3 = fmaxf(fmaxf(sb[12], sb[13]), fmaxf(sb[14], sb[15]));
      mt = fmaxf(fmaxf(fmaxf(a0, a1), fmaxf(a2, a3)),
                 fmaxf(fmaxf(b0, b1), fmaxf(b2, b3)));
      mt = xhalf_max(mt);
    }
    // defer-max (T13): skip O-rescale while tile max stays within 2^8 of m
    if (!__all(mt - m <= 8.0f)) {
      const float mn = fmaxf(m, mt);
      const float al = __builtin_amdgcn_exp2f(m - mn);
      m = mn;
      lsum *= al;
#pragma unroll
      for (int dt = 0; dt < 4; ++dt)
#pragma unroll
        for (int i = 0; i < 16; ++i) oacc[dt][i] *= al;
    }
#pragma unroll
    for (int i = 0; i < 16; ++i) sa[i] = __builtin_amdgcn_exp2f(sa[i] - m);
#pragma unroll
    for (int i = 0; i < 16; ++i) sb[i] = __builtin_amdgcn_exp2f(sb[i] - m);
    float r0 = 0.f, r1 = 0.f, r2 = 0.f, r3 = 0.f;
#pragma unroll
    for (int i = 0; i < 4; ++i) {
      r0 += sa[i]; r1 += sa[4 + i]; r2 += sa[8 + i]; r3 += sa[12 + i];
    }
#pragma unroll
    for (int i = 0; i < 4; ++i) {
      r0 += sb[i]; r1 += sb[4 + i]; r2 += sb[8 + i]; r3 += sb[12 + i];
    }
    lsum += xhalf_sum((r0 + r1) + (r2 + r3));

    // ---- P^T fragments: chunk c covers keys 16c..16c+15
    bf16x8 pf[4];
    pf[0] = build_pfrag<0>(sa);
    pf[1] = build_pfrag<2>(sa);
    pf[2] = build_pfrag<0>(sb);
    pf[3] = build_pfrag<2>(sb);

    // ---- PV: O^T[d][q] += V^T[d][k] * P^T[k][q]
#pragma unroll
    for (int dt = 0; dt < 4; ++dt) {
      const int d = dt * 32 + l31;
#pragma unroll
      for (int c = 0; c < 4; ++c) {
        bf16x8 vf = *(const bf16x8*)(VsB + ((d * 128 + c * 32 + hi * 16) ^ ((d & 7) << 4)));
        oacc[dt] = __builtin_amdgcn_mfma_f32_32x32x16_bf16(vf, pf[c], oacc[dt], 0, 0, 0);
      }
    }

    __syncthreads();
    if (it < 31) stage_write();  // write-late half of async stage
    __syncthreads();
  }

  // ---- epilogue: O2[b][s][f], f = (t&7)*1024 + h*128 + d
  const float inv = 1.0f / lsum;
  const int t = q0w + l31;
  const size_t obase = (size_t)(b * 256 + (t >> 3)) * 8192 + (t & 7) * 1024 + h * 128;
#pragma unroll
  for (int dt = 0; dt < 4; ++dt) {
#pragma unroll
    for (int g = 0; g < 4; ++g) {
      const int d = dt * 32 + 8 * g + 4 * hi;
      bf16x4 ov;
#pragma unroll
      for (int r = 0; r < 4; ++r) ov[r] = (bf16)(oacc[dt][g * 4 + r] * inv);
      *(bf16x4*)(O2 + obase + d) = ov;
    }
  }
}

extern "C" void kernel_launch(void* const* d_in, const int* in_sizes, int n_in,
                              void* d_out, int out_size, void* d_ws, size_t ws_size,
                              hipStream_t stream) {
  const float* query = (const float*)d_in[0];
  const float* key_ = (const float*)d_in[1];
  const float* value = (const float*)d_in[2];
  const float* Wq = (const float*)d_in[3];
  const float* bq = (const float*)d_in[4];
  const float* Wk = (const float*)d_in[5];
  const float* bk = (const float*)d_in[6];
  const float* Wv = (const float*)d_in[7];
  const float* bv = (const float*)d_in[8];
  const float* Wfc = (const float*)d_in[9];
  const float* bfc = (const float*)d_in[10];
  float* out = (float*)d_out;  // output dtype is FLOAT32 (verified round 7)

  const size_t T8M = (size_t)8 * 1024 * 1024;  // 8M bf16 = 16MB per region
  bf16* Qws = (bf16*)d_ws;
  bf16* Kws = Qws + T8M;
  bf16* Vtw = Kws + T8M;
  bf16* O2 = Vtw + T8M;  // 64MB total (ws_size >= 64MB verified round 5)
  // split-K partials (8 x 1024x1024 f32 = 32MB) reuse Q/K regions, which are
  // dead after attn_kernel.
  float* Pk = (float*)d_ws;

  // Fold 1/sqrt(HID) and log2(e) into Q so attention softmax runs in the
  // exp2 domain with no per-element scaling.
  const float QSC = 1.4426950408889634f / 32.0f;

  dim3 blk(256);
  // projections: M=1024, N=8192, K=1024 -> 512 blocks (f32 A, f32 B)
  gemm_nt<1, true, true, bf16><<<512, blk, 0, stream>>>(query, Wq, bq, Qws, 1024, 8192, 1024, QSC);
  gemm_nt<1, true, true, bf16><<<512, blk, 0, stream>>>(key_, Wk, bk, Kws, 1024, 8192, 1024, 1.0f);
  gemm_nt<2, true, true, bf16><<<512, blk, 0, stream>>>(value, Wv, bv, Vtw, 1024, 8192, 1024, 1.0f);
  // attention: 32 (b,h) x 16 q-chunks of 128 rows
  attn_kernel<<<512, blk, 0, stream>>>(Qws, Kws, Vtw, O2);
  // output projection, split-K x8: grid (64 tiles, 8 K-slices)
  gemm_nt<3, false, true, float><<<dim3(64, 8), blk, 0, stream>>>(O2, Wfc, nullptr, Pk, 1024, 1024, 8192, 1.0f);
  splitk_reduce<<<1024, blk, 0, stream>>>(Pk, bfc, out);
}